// Round 4
// baseline (1267.357 us; speedup 1.0000x reference)
//
#include <hip/hip_runtime.h>
#include <hip/hip_bf16.h>
#include <stdint.h>

#define T_TOK 8192
#define DIM   2048
#define NEXP  8
#define HDIM  1408
#define SHDIM 2816

typedef __attribute__((ext_vector_type(8))) short bfrag;   // 8 x bf16 (4 VGPR)
typedef __attribute__((ext_vector_type(4))) float f32x4;
typedef __attribute__((ext_vector_type(4))) short s16x4;

__device__ __forceinline__ short f2bf(float f) {
    union { float f; uint32_t u; } v; v.f = f;
    return (short)((v.u + 0x8000u) >> 16);   // round-half-up bf16
}
__device__ __forceinline__ float bf2f(short s) {
    union { uint32_t u; float f; } v; v.u = ((uint32_t)(uint16_t)s) << 16;
    return v.f;
}

__device__ __forceinline__ bfrag cvt8(float4 a, float4 b) {
    bfrag r;
    r[0] = f2bf(a.x); r[1] = f2bf(a.y); r[2] = f2bf(a.z); r[3] = f2bf(a.w);
    r[4] = f2bf(b.x); r[5] = f2bf(b.y); r[6] = f2bf(b.z); r[7] = f2bf(b.w);
    return r;
}

__device__ __forceinline__ void gload16(const void* g, void* l) {
    __builtin_amdgcn_global_load_lds(
        (__attribute__((address_space(1))) void*)(g),
        (__attribute__((address_space(3))) void*)(l), 16, 0, 0);
}

#define MFMA16(a, b, c) __builtin_amdgcn_mfma_f32_16x16x32_bf16((a), (b), (c), 0, 0, 0)
// 16B-slot swizzle for 64B (4-slot) LDS rows: 2-way max bank aliasing (free).
#define SWZ4(r) (((r) & 3) ^ (((r) >> 2) & 3))

// meta: ints [0..7] counts, [8..15] cursor, [16..24] offsets; floats at +32: s_e[8]

__global__ __launch_bounds__(256) void gate_kernel(
    const float* __restrict__ x, const float* __restrict__ gw,
    __hip_bfloat16* __restrict__ xbf,
    int* __restrict__ sel, int* __restrict__ meta, float* __restrict__ s_e)
{
    __shared__ float g[NEXP * DIM];            // 64 KB
    for (int i = threadIdx.x; i < NEXP * DIM; i += 256) g[i] = gw[i];
    __syncthreads();
    const int wid = threadIdx.x >> 6, lane = threadIdx.x & 63;
    for (int it = 0; it < 8; ++it) {
        const int t = blockIdx.x * 32 + wid * 8 + it;
        float acc[NEXP];
#pragma unroll
        for (int e = 0; e < NEXP; ++e) acc[e] = 0.f;
        const float4* xr = (const float4*)(x + (size_t)t * DIM);
        for (int j = 0; j < DIM / 4; j += 64) {
            float4 xv = xr[j + lane];
            s16x4 xv16 = { f2bf(xv.x), f2bf(xv.y), f2bf(xv.z), f2bf(xv.w) };
            *(s16x4*)&xbf[(size_t)t * DIM + (j + lane) * 4] = xv16;
#pragma unroll
            for (int e = 0; e < NEXP; ++e) {
                float4 gv = *(const float4*)&g[e * DIM + (j + lane) * 4];
                acc[e] += xv.x * gv.x + xv.y * gv.y + xv.z * gv.z + xv.w * gv.w;
            }
        }
#pragma unroll
        for (int e = 0; e < NEXP; ++e)
            for (int o = 32; o; o >>= 1) acc[e] += __shfl_xor(acc[e], o);
        if (lane == 0) {
            int e0 = 0; float v0 = acc[0];
#pragma unroll
            for (int e = 1; e < NEXP; ++e) if (acc[e] > v0) { v0 = acc[e]; e0 = e; }
            int e1 = -1; float v1 = -3.4e38f;
#pragma unroll
            for (int e = 0; e < NEXP; ++e) if (e != e0 && acc[e] > v1) { v1 = acc[e]; e1 = e; }
            float p0 = 1.f / (1.f + __expf(v1 - v0));
            float p1 = 1.f - p0;
            sel[2 * t] = e0; sel[2 * t + 1] = e1;
            atomicAdd(&s_e[e0], p0); atomicAdd(&s_e[e1], p1);
            atomicAdd(&meta[e0], 1); atomicAdd(&meta[e1], 1);
        }
    }
}

__global__ void scan_kernel(int* meta) {
    if (threadIdx.x == 0) {
        int acc = 0;
        for (int e = 0; e < NEXP; ++e) {
            meta[16 + e] = acc;
            meta[8 + e]  = acc;
            acc += meta[e];
        }
        meta[24] = acc;
    }
}

__global__ __launch_bounds__(256) void fill_kernel(
    const int* __restrict__ sel, int* __restrict__ meta,
    int* __restrict__ list, int2* __restrict__ slots)
{
    const int t = blockIdx.x * 256 + threadIdx.x;
    int e0 = sel[2 * t], e1 = sel[2 * t + 1];
    int p0 = atomicAdd(&meta[8 + e0], 1); list[p0] = t;
    int p1 = atomicAdd(&meta[8 + e1], 1); list[p1] = t;
    slots[t] = make_int2(p0, p1);
}

// one fused fp32->bf16 conversion for the 6 weight tensors
#define C1 2883584
#define C2 5767168
#define C3 8650752
#define C4 9371648
#define C5 10092544
#define C6 10813440
__global__ __launch_bounds__(256) void cvt6_kernel(
    const float* __restrict__ s0, const float* __restrict__ s1, const float* __restrict__ s2,
    const float* __restrict__ s3, const float* __restrict__ s4, const float* __restrict__ s5,
    __hip_bfloat16* __restrict__ d0, __hip_bfloat16* __restrict__ d1, __hip_bfloat16* __restrict__ d2,
    __hip_bfloat16* __restrict__ d3, __hip_bfloat16* __restrict__ d4, __hip_bfloat16* __restrict__ d5)
{
    const int stride = gridDim.x * 256;
    for (int i = blockIdx.x * 256 + threadIdx.x; i < C6; i += stride) {
        const float* s; __hip_bfloat16* d; int off;
        if      (i < C1) { s = s0; d = d0; off = i; }
        else if (i < C2) { s = s1; d = d1; off = i - C1; }
        else if (i < C3) { s = s2; d = d2; off = i - C2; }
        else if (i < C4) { s = s3; d = d3; off = i - C3; }
        else if (i < C5) { s = s4; d = d4; off = i - C4; }
        else             { s = s5; d = d5; off = i - C5; }
        const float4* p = (const float4*)(s + (size_t)off * 8);
        float4 a = p[0], b = p[1];
        *(bfrag*)(d + (size_t)off * 8) = cvt8(a, b);
    }
}

// ============ counted-vmcnt 2-sub-phase MFMA GEMMs ============
// Per K-tile (BK=64): two phases (kk halves). Phase: {ds_read own half;
// issue next tile's same half (4 gload_lds) into buf^1; s_barrier;
// setprio(1)+32 MFMA+setprio(0); s_waitcnt vmcnt(4); s_barrier}.
// Never drains to 0 in the loop. All waves issue identical load counts.

// fused gate+up: act = silu(X@W1^T) * (X@W3^T). BM=256, BN=128, BK=64.
template<int N, bool GATHER>
__global__ __launch_bounds__(512, 2) void up_v4(
    const __hip_bfloat16* __restrict__ X,
    const __hip_bfloat16* __restrict__ W1,
    const __hip_bfloat16* __restrict__ W3,
    __hip_bfloat16* __restrict__ act,
    const int* __restrict__ list,
    const int* __restrict__ meta)
{
    constexpr int K = DIM;
    constexpr int NT = K / 64;
    constexpr int nx = N / 128, ny = T_TOK / 256, nz = GATHER ? NEXP : 1;
    constexpr int nwg = nx * ny * nz, cpx = nwg / 8;
    const int bid = (int)blockIdx.x + nx * ((int)blockIdx.y + ny * (int)blockIdx.z);
    const int virt = (bid & 7) * cpx + (bid >> 3);
    const int xi = virt % nx;
    const int rest = virt / nx;
    const int yi = rest % ny;
    const int e = rest / ny;

    int count, base;
    if (GATHER) {
        count = meta[e]; base = meta[16 + e];
        if (yi * 256 >= count) return;
    } else { count = T_TOK; base = 0; }
    const int m0 = yi * 256, n0 = xi * 128;

    __shared__ alignas(16) short As[2][2][256 * 32];   // 64 KB
    __shared__ alignas(16) short B1s[2][2][128 * 32];  // 32 KB
    __shared__ alignas(16) short B3s[2][2][128 * 32];  // 32 KB

    const int tid = threadIdx.x, wid = tid >> 6, lane = tid & 63;
    const int srow = tid >> 2, dslot = tid & 3;
    const int sswz = dslot ^ SWZ4(srow);

    const __hip_bfloat16* pA[2];
#pragma unroll
    for (int q = 0; q < 2; ++q) {
        int r = m0 + q * 128 + srow; if (r > count - 1) r = count - 1;
        int ga = GATHER ? list[base + r] : r;
        pA[q] = X + (size_t)ga * K + sswz * 8;
    }
    const __hip_bfloat16* pB1 = W1 + ((size_t)e * N + n0 + srow) * K + sswz * 8;
    const __hip_bfloat16* pB3 = W3 + ((size_t)e * N + n0 + srow) * K + sswz * 8;

#define STAGE_UP(K0, KK, BUF) do {                                              \
    gload16(pA[0] + (K0) + (KK) * 32, &As[BUF][KK][tid * 8]);                   \
    gload16(pA[1] + (K0) + (KK) * 32, &As[BUF][KK][4096 + tid * 8]);            \
    gload16(pB1   + (K0) + (KK) * 32, &B1s[BUF][KK][tid * 8]);                  \
    gload16(pB3   + (K0) + (KK) * 32, &B3s[BUF][KK][tid * 8]); } while (0)

    const int wm = wid >> 2, wn = wid & 3;
    const int l15 = lane & 15, lhi = lane >> 4;
    const int lswz = (lhi ^ SWZ4(l15)) * 8;   // short offset of this lane's 16B slot

    f32x4 accg[8][2], accu[8][2];
#pragma unroll
    for (int i = 0; i < 8; ++i)
#pragma unroll
        for (int j = 0; j < 2; ++j) { accg[i][j] = 0.f; accu[i][j] = 0.f; }

    // prologue: tile 0 (both halves); keep 4 outstanding
    STAGE_UP(0, 0, 0);
    STAGE_UP(0, 1, 0);
    asm volatile("s_waitcnt vmcnt(4)" ::: "memory");
    __builtin_amdgcn_s_barrier();
    __builtin_amdgcn_sched_barrier(0);

#pragma unroll 1
    for (int t = 0; t < NT; ++t) {
        const int cur = t & 1;
        const int tpk0 = (t + 1 < NT ? t + 1 : NT - 1) * 64;
#pragma unroll
        for (int kk = 0; kk < 2; ++kk) {
            bfrag b1f[2], b3f[2];
#pragma unroll
            for (int j = 0; j < 2; ++j) {
                int rb = wn * 32 + j * 16 + l15;
                b1f[j] = *(const bfrag*)&B1s[cur][kk][rb * 32 + lswz];
                b3f[j] = *(const bfrag*)&B3s[cur][kk][rb * 32 + lswz];
            }
            STAGE_UP(tpk0, kk, cur ^ 1);
            __builtin_amdgcn_s_barrier();
            __builtin_amdgcn_s_setprio(1);
#pragma unroll
            for (int i = 0; i < 8; ++i) {
                int ra = wm * 128 + i * 16 + l15;
                bfrag a = *(const bfrag*)&As[cur][kk][ra * 32 + lswz];
#pragma unroll
                for (int j = 0; j < 2; ++j) {
                    accg[i][j] = MFMA16(a, b1f[j], accg[i][j]);
                    accu[i][j] = MFMA16(a, b3f[j], accu[i][j]);
                }
            }
            __builtin_amdgcn_s_setprio(0);
            asm volatile("s_waitcnt vmcnt(4)" ::: "memory");
            __builtin_amdgcn_s_barrier();
            __builtin_amdgcn_sched_barrier(0);
        }
    }
#undef STAGE_UP
    asm volatile("s_waitcnt vmcnt(0)" ::: "memory");

#pragma unroll
    for (int i = 0; i < 8; ++i)
#pragma unroll
        for (int r = 0; r < 4; ++r) {
            int m = wm * 128 + i * 16 + lhi * 4 + r;
            if (m0 + m < count) {
#pragma unroll
                for (int j = 0; j < 2; ++j) {
                    float gg = accg[i][j][r];
                    float uu = accu[i][j][r];
                    float a = gg / (1.f + __expf(-gg)) * uu;   // silu(g)*u
                    int n = n0 + wn * 32 + j * 16 + l15;
                    act[(size_t)(base + m0 + m) * N + n] = __float2bfloat16(a);
                }
            }
        }
}

// down: y = A @ W2^T. BM=256, BN=256, BK=64.
// TO_BF16: store unscaled bf16 rows to yscr (expert path; combine applies s_e).
// else:    store f32 rows straight to out (shared path, scale 1).
template<int KD, bool TO_BF16>
__global__ __launch_bounds__(512, 2) void down_v4(
    const __hip_bfloat16* __restrict__ A,
    const __hip_bfloat16* __restrict__ W2,
    float* __restrict__ out,
    __hip_bfloat16* __restrict__ yscr,
    const int* __restrict__ meta)
{
    constexpr int N = DIM;
    constexpr int NT = KD / 64;
    constexpr int nx = N / 256, ny = T_TOK / 256, nz = TO_BF16 ? NEXP : 1;
    constexpr int nwg = nx * ny * nz, cpx = nwg / 8;
    const int bid = (int)blockIdx.x + nx * ((int)blockIdx.y + ny * (int)blockIdx.z);
    const int virt = (bid & 7) * cpx + (bid >> 3);
    const int xi = virt % nx;
    const int rest = virt / nx;
    const int yi = rest % ny;
    const int e = rest / ny;

    int count, base;
    if (TO_BF16) {
        count = meta[e]; base = meta[16 + e];
        if (yi * 256 >= count) return;
    } else { count = T_TOK; base = 0; }
    const int m0 = yi * 256, n0 = xi * 256;

    __shared__ alignas(16) short As[2][2][256 * 32];   // 64 KB
    __shared__ alignas(16) short Bs[2][2][256 * 32];   // 64 KB

    const int tid = threadIdx.x, wid = tid >> 6, lane = tid & 63;
    const int srow = tid >> 2, dslot = tid & 3;
    const int sswz = dslot ^ SWZ4(srow);

    const __hip_bfloat16* pA[2];
    const __hip_bfloat16* pB[2];
#pragma unroll
    for (int q = 0; q < 2; ++q) {
        int r = m0 + q * 128 + srow; if (r > count - 1) r = count - 1;
        pA[q] = A  + (size_t)(base + r) * KD + sswz * 8;
        pB[q] = W2 + ((size_t)e * N + n0 + q * 128 + srow) * KD + sswz * 8;
    }

#define STAGE_DN(K0, KK, BUF) do {                                              \
    gload16(pA[0] + (K0) + (KK) * 32, &As[BUF][KK][tid * 8]);                   \
    gload16(pA[1] + (K0) + (KK) * 32, &As[BUF][KK][4096 + tid * 8]);            \
    gload16(pB[0] + (K0) + (KK) * 32, &Bs[BUF][KK][tid * 8]);                   \
    gload16(pB[1] + (K0) + (KK) * 32, &Bs[BUF][KK][4096 + tid * 8]); } while (0)

    const int wm = wid >> 2, wn = wid & 3;
    const int l15 = lane & 15, lhi = lane >> 4;
    const int lswz = (lhi ^ SWZ4(l15)) * 8;

    f32x4 acc[8][4];
#pragma unroll
    for (int i = 0; i < 8; ++i)
#pragma unroll
        for (int j = 0; j < 4; ++j) acc[i][j] = 0.f;

    STAGE_DN(0, 0, 0);
    STAGE_DN(0, 1, 0);
    asm volatile("s_waitcnt vmcnt(4)" ::: "memory");
    __builtin_amdgcn_s_barrier();
    __builtin_amdgcn_sched_barrier(0);

#pragma unroll 1
    for (int t = 0; t < NT; ++t) {
        const int cur = t & 1;
        const int tpk0 = (t + 1 < NT ? t + 1 : NT - 1) * 64;
#pragma unroll
        for (int kk = 0; kk < 2; ++kk) {
            bfrag bf[4];
#pragma unroll
            for (int j = 0; j < 4; ++j) {
                int rb = wn * 64 + j * 16 + l15;
                bf[j] = *(const bfrag*)&Bs[cur][kk][rb * 32 + lswz];
            }
            STAGE_DN(tpk0, kk, cur ^ 1);
            __builtin_amdgcn_s_barrier();
            __builtin_amdgcn_s_setprio(1);
#pragma unroll
            for (int i = 0; i < 8; ++i) {
                int ra = wm * 128 + i * 16 + l15;
                bfrag a = *(const bfrag*)&As[cur][kk][ra * 32 + lswz];
#pragma unroll
                for (int j = 0; j < 4; ++j)
                    acc[i][j] = MFMA16(a, bf[j], acc[i][j]);
            }
            __builtin_amdgcn_s_setprio(0);
            asm volatile("s_waitcnt vmcnt(4)" ::: "memory");
            __builtin_amdgcn_s_barrier();
            __builtin_amdgcn_sched_barrier(0);
        }
    }
#undef STAGE_DN
    asm volatile("s_waitcnt vmcnt(0)" ::: "memory");

#pragma unroll
    for (int i = 0; i < 8; ++i)
#pragma unroll
        for (int r = 0; r < 4; ++r) {
            int m = wm * 128 + i * 16 + lhi * 4 + r;
            if (m0 + m < count) {
#pragma unroll
                for (int j = 0; j < 4; ++j) {
                    int n = n0 + wn * 64 + j * 16 + l15;
                    if (TO_BF16)
                        yscr[(size_t)(base + m0 + m) * DIM + n] = __float2bfloat16(acc[i][j][r]);
                    else
                        out[(size_t)(m0 + m) * DIM + n] = acc[i][j][r];
                }
            }
        }
}

// out[t] += s_e[e0]*y[slot0] + s_e[e1]*y[slot1]
__global__ __launch_bounds__(256) void combine_kernel(
    float* __restrict__ out, const __hip_bfloat16* __restrict__ yscr,
    const int* __restrict__ sel, const int2* __restrict__ slots,
    const float* __restrict__ s_e)
{
    const int t = blockIdx.x;
    const int d = threadIdx.x * 8;
    const int2 sl = slots[t];
    const float se0 = s_e[sel[2 * t]];
    const float se1 = s_e[sel[2 * t + 1]];
    bfrag y0 = *(const bfrag*)&yscr[(size_t)sl.x * DIM + d];
    bfrag y1 = *(const bfrag*)&yscr[(size_t)sl.y * DIM + d];
    float4* o = (float4*)(out + (size_t)t * DIM + d);
    float4 o0 = o[0], o1 = o[1];
    o0.x += se0 * bf2f(y0[0]) + se1 * bf2f(y1[0]);
    o0.y += se0 * bf2f(y0[1]) + se1 * bf2f(y1[1]);
    o0.z += se0 * bf2f(y0[2]) + se1 * bf2f(y1[2]);
    o0.w += se0 * bf2f(y0[3]) + se1 * bf2f(y1[3]);
    o1.x += se0 * bf2f(y0[4]) + se1 * bf2f(y1[4]);
    o1.y += se0 * bf2f(y0[5]) + se1 * bf2f(y1[5]);
    o1.z += se0 * bf2f(y0[6]) + se1 * bf2f(y1[6]);
    o1.w += se0 * bf2f(y0[7]) + se1 * bf2f(y1[7]);
    o[0] = o0; o[1] = o1;
}

extern "C" void kernel_launch(void* const* d_in, const int* in_sizes, int n_in,
                              void* d_out, int out_size, void* d_ws, size_t ws_size,
                              hipStream_t stream) {
    const float* x   = (const float*)d_in[0];
    const float* gw  = (const float*)d_in[1];
    const float* w1  = (const float*)d_in[2];
    const float* w3  = (const float*)d_in[3];
    const float* w2  = (const float*)d_in[4];
    const float* sw1 = (const float*)d_in[5];
    const float* sw3 = (const float*)d_in[6];
    const float* sw2 = (const float*)d_in[7];
    float* out = (float*)d_out;

    const size_t SZ_X   = (size_t)T_TOK * DIM * 2;            // 32 MB
    const size_t SZ_W   = (size_t)NEXP * HDIM * DIM * 2;      // 46.1 MB each
    const size_t SZ_SW  = (size_t)SHDIM * DIM * 2;            // 11.5 MB each
    const size_t SZ_ACT = (size_t)2 * T_TOK * HDIM * 2;       // 46.1 MB
    const size_t need = SZ_X + 3 * SZ_W + 3 * SZ_SW + SZ_ACT
                      + (size_t)4 * T_TOK * sizeof(int)
                      + (size_t)2 * T_TOK * sizeof(int) /*slots*/ + 512;
    if (need > ws_size) return;

    char* p = (char*)d_ws;
    __hip_bfloat16* xbf   = (__hip_bfloat16*)p; p += SZ_X;
    __hip_bfloat16* w1bf  = (__hip_bfloat16*)p; p += SZ_W;
    __hip_bfloat16* w3bf  = (__hip_bfloat16*)p; p += SZ_W;
    __hip_bfloat16* w2bf  = (__hip_bfloat16*)p; p += SZ_W;
    __hip_bfloat16* sw1bf = (__hip_bfloat16*)p; p += SZ_SW;
    __hip_bfloat16* sw3bf = (__hip_bfloat16*)p; p += SZ_SW;
    __hip_bfloat16* sw2bf = (__hip_bfloat16*)p; p += SZ_SW;
    __hip_bfloat16* act   = (__hip_bfloat16*)p; p += SZ_ACT;
    int*  list  = (int*)p;  p += (size_t)2 * T_TOK * sizeof(int);
    int*  sel   = (int*)p;  p += (size_t)2 * T_TOK * sizeof(int);
    int2* slots = (int2*)p; p += (size_t)2 * T_TOK * sizeof(int);
    int*  meta  = (int*)p;
    float* s_e  = (float*)(meta + 32);
    // y scratch (16384 x 2048 bf16 = 64 MB) aliases xbf+w1bf (dead after expert-up)
    __hip_bfloat16* yscr = (__hip_bfloat16*)d_ws;

    hipMemsetAsync(meta, 0, 256, stream);
    gate_kernel<<<T_TOK / 32, 256, 0, stream>>>(x, gw, xbf, sel, meta, s_e);
    scan_kernel<<<1, 64, 0, stream>>>(meta);
    fill_kernel<<<T_TOK / 256, 256, 0, stream>>>(sel, meta, list, slots);

    cvt6_kernel<<<2048, 256, 0, stream>>>(w1, w3, w2, sw1, sw3, sw2,
                                          w1bf, w3bf, w2bf, sw1bf, sw3bf, sw2bf);

    // shared expert first (plain f32 stores init out)
    up_v4<SHDIM, false><<<dim3(SHDIM / 128, T_TOK / 256, 1), 512, 0, stream>>>(
        xbf, sw1bf, sw3bf, act, nullptr, meta);
    down_v4<SHDIM, false><<<dim3(DIM / 256, T_TOK / 256, 1), 512, 0, stream>>>(
        act, sw2bf, out, nullptr, meta);
    // sparse experts: act -> y (bf16, unscaled) -> combine with s_e scales
    up_v4<HDIM, true><<<dim3(HDIM / 128, T_TOK / 256, NEXP), 512, 0, stream>>>(
        xbf, w1bf, w3bf, act, list, meta);
    down_v4<HDIM, true><<<dim3(DIM / 256, T_TOK / 256, NEXP), 512, 0, stream>>>(
        act, w2bf, out, yscr, meta);
    combine_kernel<<<T_TOK, 256, 0, stream>>>(out, yscr, sel, slots, s_e);
}

// Round 5
// 1217.865 us; speedup vs baseline: 1.0406x; 1.0406x over previous
//
#include <hip/hip_runtime.h>
#include <hip/hip_bf16.h>
#include <stdint.h>

#define T_TOK 8192
#define DIM   2048
#define NEXP  8
#define HDIM  1408
#define SHDIM 2816

typedef __attribute__((ext_vector_type(8))) short bfrag;   // 8 x bf16 (4 VGPR)
typedef __attribute__((ext_vector_type(4))) float f32x4;
typedef __attribute__((ext_vector_type(4))) short s16x4;

__device__ __forceinline__ short f2bf(float f) {
    union { float f; uint32_t u; } v; v.f = f;
    return (short)((v.u + 0x8000u) >> 16);   // round-half-up bf16
}
__device__ __forceinline__ float bf2f(short s) {
    union { uint32_t u; float f; } v; v.u = ((uint32_t)(uint16_t)s) << 16;
    return v.f;
}

__device__ __forceinline__ bfrag cvt8(float4 a, float4 b) {
    bfrag r;
    r[0] = f2bf(a.x); r[1] = f2bf(a.y); r[2] = f2bf(a.z); r[3] = f2bf(a.w);
    r[4] = f2bf(b.x); r[5] = f2bf(b.y); r[6] = f2bf(b.z); r[7] = f2bf(b.w);
    return r;
}

__device__ __forceinline__ void gload16(const void* g, void* l) {
    __builtin_amdgcn_global_load_lds(
        (__attribute__((address_space(1))) void*)(g),
        (__attribute__((address_space(3))) void*)(l), 16, 0, 0);
}

#define MFMA16(a, b, c) __builtin_amdgcn_mfma_f32_16x16x32_bf16((a), (b), (c), 0, 0, 0)

// meta: ints [0..7] counts, [8..15] cursor, [16..24] offsets; floats at +32: s_e[8]

__global__ __launch_bounds__(256) void gate_kernel(
    const float* __restrict__ x, const float* __restrict__ gw,
    __hip_bfloat16* __restrict__ xbf,
    int* __restrict__ sel, int* __restrict__ meta, float* __restrict__ s_e)
{
    __shared__ float g[NEXP * DIM];            // 64 KB
    for (int i = threadIdx.x; i < NEXP * DIM; i += 256) g[i] = gw[i];
    __syncthreads();
    const int wid = threadIdx.x >> 6, lane = threadIdx.x & 63;
    for (int it = 0; it < 8; ++it) {
        const int t = blockIdx.x * 32 + wid * 8 + it;
        float acc[NEXP];
#pragma unroll
        for (int e = 0; e < NEXP; ++e) acc[e] = 0.f;
        const float4* xr = (const float4*)(x + (size_t)t * DIM);
        for (int j = 0; j < DIM / 4; j += 64) {
            float4 xv = xr[j + lane];
            s16x4 xv16 = { f2bf(xv.x), f2bf(xv.y), f2bf(xv.z), f2bf(xv.w) };
            *(s16x4*)&xbf[(size_t)t * DIM + (j + lane) * 4] = xv16;
#pragma unroll
            for (int e = 0; e < NEXP; ++e) {
                float4 gv = *(const float4*)&g[e * DIM + (j + lane) * 4];
                acc[e] += xv.x * gv.x + xv.y * gv.y + xv.z * gv.z + xv.w * gv.w;
            }
        }
#pragma unroll
        for (int e = 0; e < NEXP; ++e)
            for (int o = 32; o; o >>= 1) acc[e] += __shfl_xor(acc[e], o);
        if (lane == 0) {
            int e0 = 0; float v0 = acc[0];
#pragma unroll
            for (int e = 1; e < NEXP; ++e) if (acc[e] > v0) { v0 = acc[e]; e0 = e; }
            int e1 = -1; float v1 = -3.4e38f;
#pragma unroll
            for (int e = 0; e < NEXP; ++e) if (e != e0 && acc[e] > v1) { v1 = acc[e]; e1 = e; }
            float p0 = 1.f / (1.f + __expf(v1 - v0));
            float p1 = 1.f - p0;
            sel[2 * t] = e0; sel[2 * t + 1] = e1;
            atomicAdd(&s_e[e0], p0); atomicAdd(&s_e[e1], p1);
            atomicAdd(&meta[e0], 1); atomicAdd(&meta[e1], 1);
        }
    }
}

__global__ void scan_kernel(int* meta) {
    if (threadIdx.x == 0) {
        int acc = 0;
        for (int e = 0; e < NEXP; ++e) {
            meta[16 + e] = acc;
            meta[8 + e]  = acc;
            acc += meta[e];
        }
        meta[24] = acc;
    }
}

__global__ __launch_bounds__(256) void fill_kernel(
    const int* __restrict__ sel, int* __restrict__ meta,
    int* __restrict__ list, int2* __restrict__ slots)
{
    const int t = blockIdx.x * 256 + threadIdx.x;
    int e0 = sel[2 * t], e1 = sel[2 * t + 1];
    int p0 = atomicAdd(&meta[8 + e0], 1); list[p0] = t;
    int p1 = atomicAdd(&meta[8 + e1], 1); list[p1] = t;
    slots[t] = make_int2(p0, p1);
}

// one fused fp32->bf16 conversion for the 6 weight tensors
#define C1 2883584
#define C2 5767168
#define C3 8650752
#define C4 9371648
#define C5 10092544
#define C6 10813440
__global__ __launch_bounds__(256) void cvt6_kernel(
    const float* __restrict__ s0, const float* __restrict__ s1, const float* __restrict__ s2,
    const float* __restrict__ s3, const float* __restrict__ s4, const float* __restrict__ s5,
    __hip_bfloat16* __restrict__ d0, __hip_bfloat16* __restrict__ d1, __hip_bfloat16* __restrict__ d2,
    __hip_bfloat16* __restrict__ d3, __hip_bfloat16* __restrict__ d4, __hip_bfloat16* __restrict__ d5)
{
    const int stride = gridDim.x * 256;
    for (int i = blockIdx.x * 256 + threadIdx.x; i < C6; i += stride) {
        const float* s; __hip_bfloat16* d; int off;
        if      (i < C1) { s = s0; d = d0; off = i; }
        else if (i < C2) { s = s1; d = d1; off = i - C1; }
        else if (i < C3) { s = s2; d = d2; off = i - C2; }
        else if (i < C4) { s = s3; d = d3; off = i - C3; }
        else if (i < C5) { s = s4; d = d4; off = i - C4; }
        else             { s = s5; d = d5; off = i - C5; }
        const float4* p = (const float4*)(s + (size_t)off * 8);
        float4 a = p[0], b = p[1];
        *(bfrag*)(d + (size_t)off * 8) = cvt8(a, b);
    }
}

// ============ counted-vmcnt 2-sub-phase MFMA GEMMs, 128B-pitch LDS ============
// kk-region layout (virtual row pairing, R3-class XOR):
//   L(row,slot16) = (row>>1)*128 + (((slot + 4*(row&1)) ^ ((row>>1)&7)) << 4)
// Stage dest is linear (lane-slot L = 16*lambda); source applies the inverse:
//   u = (lambda&7) ^ ((lambda>>3)&7); row = 2*(lambda>>3)+(u>>2); slot = u&3.
// Read offset collapses to per-lane const: vswz = ((lhi+4*(l15&1)) ^ (l15>>1))<<4.

// fused gate+up: act = silu(X@W1^T) * (X@W3^T). BM=256, BN=128, BK=64.
template<int N, bool GATHER>
__global__ __launch_bounds__(512, 2) void up_v5(
    const __hip_bfloat16* __restrict__ X,
    const __hip_bfloat16* __restrict__ W1,
    const __hip_bfloat16* __restrict__ W3,
    __hip_bfloat16* __restrict__ act,
    const int* __restrict__ list,
    const int* __restrict__ meta)
{
    constexpr int K = DIM;
    constexpr int NT = K / 64;
    constexpr int nx = N / 128, ny = T_TOK / 256, nz = GATHER ? NEXP : 1;
    constexpr int nwg = nx * ny * nz, cpx = nwg / 8;
    const int bid = (int)blockIdx.x + nx * ((int)blockIdx.y + ny * (int)blockIdx.z);
    const int virt = (bid & 7) * cpx + (bid >> 3);
    const int xi = virt % nx;
    const int rest = virt / nx;
    const int yi = rest % ny;
    const int e = rest / ny;

    int count, base;
    if (GATHER) {
        count = meta[e]; base = meta[16 + e];
        if (yi * 256 >= count) return;
    } else { count = T_TOK; base = 0; }
    const int m0 = yi * 256, n0 = xi * 128;

    __shared__ alignas(16) short As[2][2][256 * 32];   // 64 KB
    __shared__ alignas(16) short B1s[2][2][128 * 32];  // 32 KB
    __shared__ alignas(16) short B3s[2][2][128 * 32];  // 32 KB

    const int tid = threadIdx.x, wid = tid >> 6, lane = tid & 63;

    // stage source mapping (inverse of the LDS layout)
    const int u    = (tid & 7) ^ ((tid >> 3) & 7);
    const int srow = 2 * (tid >> 3) + (u >> 2);    // 0..255 for A; 0..127 for B
    const int sslot = u & 3;                       // 16B slot within 32-short half-row

    const __hip_bfloat16* pA[2];
#pragma unroll
    for (int q = 0; q < 2; ++q) {
        int r = m0 + srow + q * 128; if (r > count - 1) r = count - 1;
        int ga = GATHER ? list[base + r] : r;
        pA[q] = X + (size_t)ga * K + sslot * 8;
    }
    const __hip_bfloat16* pB1 = W1 + ((size_t)e * N + n0 + srow) * K + sslot * 8;
    const __hip_bfloat16* pB3 = W3 + ((size_t)e * N + n0 + srow) * K + sslot * 8;

#define STAGE_UP(K0, KK, BUF) do {                                              \
    gload16(pA[0] + (K0) + (KK) * 32, &As[BUF][KK][tid * 8]);                   \
    gload16(pA[1] + (K0) + (KK) * 32, &As[BUF][KK][4096 + tid * 8]);            \
    gload16(pB1   + (K0) + (KK) * 32, &B1s[BUF][KK][tid * 8]);                  \
    gload16(pB3   + (K0) + (KK) * 32, &B3s[BUF][KK][tid * 8]); } while (0)

    const int wm = wid >> 2, wn = wid & 3;
    const int l15 = lane & 15, lhi = lane >> 4;
    // per-lane constant read swizzle (bytes)
    const int vswz = (((lhi + 4 * (l15 & 1)) ^ (l15 >> 1)) << 4);
    const int arb  = (l15 >> 1) * 128 + vswz;      // row-within-8 + slot bytes

    f32x4 accg[8][2], accu[8][2];
#pragma unroll
    for (int i = 0; i < 8; ++i)
#pragma unroll
        for (int j = 0; j < 2; ++j) { accg[i][j] = 0.f; accu[i][j] = 0.f; }

    // prologue: tile 0 (both halves); keep 4 outstanding
    STAGE_UP(0, 0, 0);
    STAGE_UP(0, 1, 0);
    asm volatile("s_waitcnt vmcnt(4)" ::: "memory");
    __builtin_amdgcn_s_barrier();
    __builtin_amdgcn_sched_barrier(0);

#pragma unroll 1
    for (int t = 0; t < NT; ++t) {
        const int cur = t & 1;
        const int tpk0 = (t + 1 < NT ? t + 1 : NT - 1) * 64;
#pragma unroll
        for (int kk = 0; kk < 2; ++kk) {
            bfrag b1f[2], b3f[2];
#pragma unroll
            for (int j = 0; j < 2; ++j) {
                const int off = wn * 2048 + j * 1024 + arb;
                b1f[j] = *(const bfrag*)((const char*)B1s[cur][kk] + off);
                b3f[j] = *(const bfrag*)((const char*)B3s[cur][kk] + off);
            }
            STAGE_UP(tpk0, kk, cur ^ 1);
            __builtin_amdgcn_s_barrier();
            __builtin_amdgcn_s_setprio(1);
#pragma unroll
            for (int i = 0; i < 8; ++i) {
                bfrag a = *(const bfrag*)((const char*)As[cur][kk] + wm * 8192 + i * 1024 + arb);
#pragma unroll
                for (int j = 0; j < 2; ++j) {
                    accg[i][j] = MFMA16(a, b1f[j], accg[i][j]);
                    accu[i][j] = MFMA16(a, b3f[j], accu[i][j]);
                }
            }
            __builtin_amdgcn_s_setprio(0);
            asm volatile("s_waitcnt vmcnt(4)" ::: "memory");
            __builtin_amdgcn_s_barrier();
            __builtin_amdgcn_sched_barrier(0);
        }
    }
#undef STAGE_UP
    asm volatile("s_waitcnt vmcnt(0)" ::: "memory");

#pragma unroll
    for (int i = 0; i < 8; ++i)
#pragma unroll
        for (int r = 0; r < 4; ++r) {
            int m = wm * 128 + i * 16 + lhi * 4 + r;
            if (m0 + m < count) {
#pragma unroll
                for (int j = 0; j < 2; ++j) {
                    float gg = accg[i][j][r];
                    float uu = accu[i][j][r];
                    float a = gg / (1.f + __expf(-gg)) * uu;   // silu(g)*u
                    int n = n0 + wn * 32 + j * 16 + l15;
                    act[(size_t)(base + m0 + m) * N + n] = __float2bfloat16(a);
                }
            }
        }
}

// down: y = A @ W2^T. BM=256, BN=256, BK=64.
// TO_BF16: store unscaled bf16 rows to yscr (expert path; combine applies s_e).
// else:    store f32 rows straight to out (shared path).
template<int KD, bool TO_BF16>
__global__ __launch_bounds__(512, 2) void down_v5(
    const __hip_bfloat16* __restrict__ A,
    const __hip_bfloat16* __restrict__ W2,
    float* __restrict__ out,
    __hip_bfloat16* __restrict__ yscr,
    const int* __restrict__ meta)
{
    constexpr int N = DIM;
    constexpr int NT = KD / 64;
    constexpr int nx = N / 256, ny = T_TOK / 256, nz = TO_BF16 ? NEXP : 1;
    constexpr int nwg = nx * ny * nz, cpx = nwg / 8;
    const int bid = (int)blockIdx.x + nx * ((int)blockIdx.y + ny * (int)blockIdx.z);
    const int virt = (bid & 7) * cpx + (bid >> 3);
    const int xi = virt % nx;
    const int rest = virt / nx;
    const int yi = rest % ny;
    const int e = rest / ny;

    int count, base;
    if (TO_BF16) {
        count = meta[e]; base = meta[16 + e];
        if (yi * 256 >= count) return;
    } else { count = T_TOK; base = 0; }
    const int m0 = yi * 256, n0 = xi * 256;

    __shared__ alignas(16) short As[2][2][256 * 32];   // 64 KB
    __shared__ alignas(16) short Bs[2][2][256 * 32];   // 64 KB

    const int tid = threadIdx.x, wid = tid >> 6, lane = tid & 63;

    const int u    = (tid & 7) ^ ((tid >> 3) & 7);
    const int srow = 2 * (tid >> 3) + (u >> 2);    // 0..255 with +128 for q=1
    const int sslot = u & 3;

    const __hip_bfloat16* pA[2];
    const __hip_bfloat16* pB[2];
#pragma unroll
    for (int q = 0; q < 2; ++q) {
        int r = m0 + srow + q * 128; if (r > count - 1) r = count - 1;
        pA[q] = A  + (size_t)(base + r) * KD + sslot * 8;
        pB[q] = W2 + ((size_t)e * N + n0 + srow + q * 128) * KD + sslot * 8;
    }

#define STAGE_DN(K0, KK, BUF) do {                                              \
    gload16(pA[0] + (K0) + (KK) * 32, &As[BUF][KK][tid * 8]);                   \
    gload16(pA[1] + (K0) + (KK) * 32, &As[BUF][KK][4096 + tid * 8]);            \
    gload16(pB[0] + (K0) + (KK) * 32, &Bs[BUF][KK][tid * 8]);                   \
    gload16(pB[1] + (K0) + (KK) * 32, &Bs[BUF][KK][4096 + tid * 8]); } while (0)

    const int wm = wid >> 2, wn = wid & 3;
    const int l15 = lane & 15, lhi = lane >> 4;
    const int vswz = (((lhi + 4 * (l15 & 1)) ^ (l15 >> 1)) << 4);
    const int arb  = (l15 >> 1) * 128 + vswz;

    f32x4 acc[8][4];
#pragma unroll
    for (int i = 0; i < 8; ++i)
#pragma unroll
        for (int j = 0; j < 4; ++j) acc[i][j] = 0.f;

    STAGE_DN(0, 0, 0);
    STAGE_DN(0, 1, 0);
    asm volatile("s_waitcnt vmcnt(4)" ::: "memory");
    __builtin_amdgcn_s_barrier();
    __builtin_amdgcn_sched_barrier(0);

#pragma unroll 1
    for (int t = 0; t < NT; ++t) {
        const int cur = t & 1;
        const int tpk0 = (t + 1 < NT ? t + 1 : NT - 1) * 64;
#pragma unroll
        for (int kk = 0; kk < 2; ++kk) {
            bfrag bf[4];
#pragma unroll
            for (int j = 0; j < 4; ++j)
                bf[j] = *(const bfrag*)((const char*)Bs[cur][kk] + wn * 4096 + j * 1024 + arb);
            STAGE_DN(tpk0, kk, cur ^ 1);
            __builtin_amdgcn_s_barrier();
            __builtin_amdgcn_s_setprio(1);
#pragma unroll
            for (int i = 0; i < 8; ++i) {
                bfrag a = *(const bfrag*)((const char*)As[cur][kk] + wm * 8192 + i * 1024 + arb);
#pragma unroll
                for (int j = 0; j < 4; ++j)
                    acc[i][j] = MFMA16(a, bf[j], acc[i][j]);
            }
            __builtin_amdgcn_s_setprio(0);
            asm volatile("s_waitcnt vmcnt(4)" ::: "memory");
            __builtin_amdgcn_s_barrier();
            __builtin_amdgcn_sched_barrier(0);
        }
    }
#undef STAGE_DN
    asm volatile("s_waitcnt vmcnt(0)" ::: "memory");

#pragma unroll
    for (int i = 0; i < 8; ++i)
#pragma unroll
        for (int r = 0; r < 4; ++r) {
            int m = wm * 128 + i * 16 + lhi * 4 + r;
            if (m0 + m < count) {
#pragma unroll
                for (int j = 0; j < 4; ++j) {
                    int n = n0 + wn * 64 + j * 16 + l15;
                    if (TO_BF16)
                        yscr[(size_t)(base + m0 + m) * DIM + n] = __float2bfloat16(acc[i][j][r]);
                    else
                        out[(size_t)(m0 + m) * DIM + n] = acc[i][j][r];
                }
            }
        }
}

// out[t] += s_e[e0]*y[slot0] + s_e[e1]*y[slot1]
__global__ __launch_bounds__(256) void combine_kernel(
    float* __restrict__ out, const __hip_bfloat16* __restrict__ yscr,
    const int* __restrict__ sel, const int2* __restrict__ slots,
    const float* __restrict__ s_e)
{
    const int t = blockIdx.x;
    const int d = threadIdx.x * 8;
    const int2 sl = slots[t];
    const float se0 = s_e[sel[2 * t]];
    const float se1 = s_e[sel[2 * t + 1]];
    bfrag y0 = *(const bfrag*)&yscr[(size_t)sl.x * DIM + d];
    bfrag y1 = *(const bfrag*)&yscr[(size_t)sl.y * DIM + d];
    float4* o = (float4*)(out + (size_t)t * DIM + d);
    float4 o0 = o[0], o1 = o[1];
    o0.x += se0 * bf2f(y0[0]) + se1 * bf2f(y1[0]);
    o0.y += se0 * bf2f(y0[1]) + se1 * bf2f(y1[1]);
    o0.z += se0 * bf2f(y0[2]) + se1 * bf2f(y1[2]);
    o0.w += se0 * bf2f(y0[3]) + se1 * bf2f(y1[3]);
    o1.x += se0 * bf2f(y0[4]) + se1 * bf2f(y1[4]);
    o1.y += se0 * bf2f(y0[5]) + se1 * bf2f(y1[5]);
    o1.z += se0 * bf2f(y0[6]) + se1 * bf2f(y1[6]);
    o1.w += se0 * bf2f(y0[7]) + se1 * bf2f(y1[7]);
    o[0] = o0; o[1] = o1;
}

extern "C" void kernel_launch(void* const* d_in, const int* in_sizes, int n_in,
                              void* d_out, int out_size, void* d_ws, size_t ws_size,
                              hipStream_t stream) {
    const float* x   = (const float*)d_in[0];
    const float* gw  = (const float*)d_in[1];
    const float* w1  = (const float*)d_in[2];
    const float* w3  = (const float*)d_in[3];
    const float* w2  = (const float*)d_in[4];
    const float* sw1 = (const float*)d_in[5];
    const float* sw3 = (const float*)d_in[6];
    const float* sw2 = (const float*)d_in[7];
    float* out = (float*)d_out;

    const size_t SZ_X   = (size_t)T_TOK * DIM * 2;            // 32 MB
    const size_t SZ_W   = (size_t)NEXP * HDIM * DIM * 2;      // 46.1 MB each
    const size_t SZ_SW  = (size_t)SHDIM * DIM * 2;            // 11.5 MB each
    const size_t SZ_ACT = (size_t)2 * T_TOK * HDIM * 2;       // 46.1 MB
    const size_t need = SZ_X + 3 * SZ_W + 3 * SZ_SW + SZ_ACT
                      + (size_t)4 * T_TOK * sizeof(int)
                      + (size_t)2 * T_TOK * sizeof(int) /*slots*/ + 512;
    if (need > ws_size) return;

    char* p = (char*)d_ws;
    __hip_bfloat16* xbf   = (__hip_bfloat16*)p; p += SZ_X;
    __hip_bfloat16* w1bf  = (__hip_bfloat16*)p; p += SZ_W;
    __hip_bfloat16* w3bf  = (__hip_bfloat16*)p; p += SZ_W;
    __hip_bfloat16* w2bf  = (__hip_bfloat16*)p; p += SZ_W;
    __hip_bfloat16* sw1bf = (__hip_bfloat16*)p; p += SZ_SW;
    __hip_bfloat16* sw3bf = (__hip_bfloat16*)p; p += SZ_SW;
    __hip_bfloat16* sw2bf = (__hip_bfloat16*)p; p += SZ_SW;
    __hip_bfloat16* act   = (__hip_bfloat16*)p; p += SZ_ACT;
    int*  list  = (int*)p;  p += (size_t)2 * T_TOK * sizeof(int);
    int*  sel   = (int*)p;  p += (size_t)2 * T_TOK * sizeof(int);
    int2* slots = (int2*)p; p += (size_t)2 * T_TOK * sizeof(int);
    int*  meta  = (int*)p;
    float* s_e  = (float*)(meta + 32);
    // y scratch (16384 x 2048 bf16 = 64 MB) aliases xbf+w1bf (dead after expert-up)
    __hip_bfloat16* yscr = (__hip_bfloat16*)d_ws;

    hipMemsetAsync(meta, 0, 256, stream);
    gate_kernel<<<T_TOK / 32, 256, 0, stream>>>(x, gw, xbf, sel, meta, s_e);
    scan_kernel<<<1, 64, 0, stream>>>(meta);
    fill_kernel<<<T_TOK / 256, 256, 0, stream>>>(sel, meta, list, slots);

    cvt6_kernel<<<2048, 256, 0, stream>>>(w1, w3, w2, sw1, sw3, sw2,
                                          w1bf, w3bf, w2bf, sw1bf, sw3bf, sw2bf);

    // shared expert first (plain f32 stores init out)
    up_v5<SHDIM, false><<<dim3(SHDIM / 128, T_TOK / 256, 1), 512, 0, stream>>>(
        xbf, sw1bf, sw3bf, act, nullptr, meta);
    down_v5<SHDIM, false><<<dim3(DIM / 256, T_TOK / 256, 1), 512, 0, stream>>>(
        act, sw2bf, out, nullptr, meta);
    // sparse experts: act -> y (bf16, unscaled) -> combine with s_e scales
    up_v5<HDIM, true><<<dim3(HDIM / 128, T_TOK / 256, NEXP), 512, 0, stream>>>(
        xbf, w1bf, w3bf, act, list, meta);
    down_v5<HDIM, true><<<dim3(DIM / 256, T_TOK / 256, NEXP), 512, 0, stream>>>(
        act, w2bf, out, yscr, meta);
    combine_kernel<<<T_TOK, 256, 0, stream>>>(out, yscr, sel, slots, s_e);
}

// Round 6
// 1118.425 us; speedup vs baseline: 1.1332x; 1.0889x over previous
//
#include <hip/hip_runtime.h>
#include <hip/hip_bf16.h>
#include <stdint.h>

#define T_TOK 8192
#define DIM   2048
#define NEXP  8
#define HDIM  1408
#define SHDIM 2816

typedef __attribute__((ext_vector_type(8))) short bfrag;   // 8 x bf16 (4 VGPR)
typedef __attribute__((ext_vector_type(4))) float f32x4;
typedef __attribute__((ext_vector_type(4))) short s16x4;

__device__ __forceinline__ short f2bf(float f) {
    union { float f; uint32_t u; } v; v.f = f;
    return (short)((v.u + 0x8000u) >> 16);   // round-half-up bf16
}
__device__ __forceinline__ float bf2f(short s) {
    union { uint32_t u; float f; } v; v.u = ((uint32_t)(uint16_t)s) << 16;
    return v.f;
}

__device__ __forceinline__ bfrag cvt8(float4 a, float4 b) {
    bfrag r;
    r[0] = f2bf(a.x); r[1] = f2bf(a.y); r[2] = f2bf(a.z); r[3] = f2bf(a.w);
    r[4] = f2bf(b.x); r[5] = f2bf(b.y); r[6] = f2bf(b.z); r[7] = f2bf(b.w);
    return r;
}

__device__ __forceinline__ void gload16(const void* g, void* l) {
    __builtin_amdgcn_global_load_lds(
        (__attribute__((address_space(1))) void*)(g),
        (__attribute__((address_space(3))) void*)(l), 16, 0, 0);
}

#define MFMA16(a, b, c) __builtin_amdgcn_mfma_f32_16x16x32_bf16((a), (b), (c), 0, 0, 0)

// meta: ints [0..7] counts, [8..15] cursor, [16..24] offsets; floats at +32: s_e[8]

__global__ __launch_bounds__(256) void gate_kernel(
    const float* __restrict__ x, const float* __restrict__ gw,
    __hip_bfloat16* __restrict__ xbf,
    int* __restrict__ sel, int* __restrict__ meta, float* __restrict__ s_e)
{
    __shared__ float g[NEXP * DIM];            // 64 KB
    for (int i = threadIdx.x; i < NEXP * DIM; i += 256) g[i] = gw[i];
    __syncthreads();
    const int wid = threadIdx.x >> 6, lane = threadIdx.x & 63;
    for (int it = 0; it < 8; ++it) {
        const int t = blockIdx.x * 32 + wid * 8 + it;
        float acc[NEXP];
#pragma unroll
        for (int e = 0; e < NEXP; ++e) acc[e] = 0.f;
        const float4* xr = (const float4*)(x + (size_t)t * DIM);
        for (int j = 0; j < DIM / 4; j += 64) {
            float4 xv = xr[j + lane];
            s16x4 xv16 = { f2bf(xv.x), f2bf(xv.y), f2bf(xv.z), f2bf(xv.w) };
            *(s16x4*)&xbf[(size_t)t * DIM + (j + lane) * 4] = xv16;
#pragma unroll
            for (int e = 0; e < NEXP; ++e) {
                float4 gv = *(const float4*)&g[e * DIM + (j + lane) * 4];
                acc[e] += xv.x * gv.x + xv.y * gv.y + xv.z * gv.z + xv.w * gv.w;
            }
        }
#pragma unroll
        for (int e = 0; e < NEXP; ++e)
            for (int o = 32; o; o >>= 1) acc[e] += __shfl_xor(acc[e], o);
        if (lane == 0) {
            int e0 = 0; float v0 = acc[0];
#pragma unroll
            for (int e = 1; e < NEXP; ++e) if (acc[e] > v0) { v0 = acc[e]; e0 = e; }
            int e1 = -1; float v1 = -3.4e38f;
#pragma unroll
            for (int e = 0; e < NEXP; ++e) if (e != e0 && acc[e] > v1) { v1 = acc[e]; e1 = e; }
            float p0 = 1.f / (1.f + __expf(v1 - v0));
            float p1 = 1.f - p0;
            sel[2 * t] = e0; sel[2 * t + 1] = e1;
            atomicAdd(&s_e[e0], p0); atomicAdd(&s_e[e1], p1);
            atomicAdd(&meta[e0], 1); atomicAdd(&meta[e1], 1);
        }
    }
}

__global__ void scan_kernel(int* meta) {
    if (threadIdx.x == 0) {
        int acc = 0;
        for (int e = 0; e < NEXP; ++e) {
            meta[16 + e] = acc;
            meta[8 + e]  = acc;
            acc += meta[e];
        }
        meta[24] = acc;
    }
}

__global__ __launch_bounds__(256) void fill_kernel(
    const int* __restrict__ sel, int* __restrict__ meta,
    int* __restrict__ list, int2* __restrict__ slots)
{
    const int t = blockIdx.x * 256 + threadIdx.x;
    int e0 = sel[2 * t], e1 = sel[2 * t + 1];
    int p0 = atomicAdd(&meta[8 + e0], 1); list[p0] = t;
    int p1 = atomicAdd(&meta[8 + e1], 1); list[p1] = t;
    slots[t] = make_int2(p0, p1);
}

// one fused fp32->bf16 conversion for the 6 weight tensors
#define C1 2883584
#define C2 5767168
#define C3 8650752
#define C4 9371648
#define C5 10092544
#define C6 10813440
__global__ __launch_bounds__(256) void cvt6_kernel(
    const float* __restrict__ s0, const float* __restrict__ s1, const float* __restrict__ s2,
    const float* __restrict__ s3, const float* __restrict__ s4, const float* __restrict__ s5,
    __hip_bfloat16* __restrict__ d0, __hip_bfloat16* __restrict__ d1, __hip_bfloat16* __restrict__ d2,
    __hip_bfloat16* __restrict__ d3, __hip_bfloat16* __restrict__ d4, __hip_bfloat16* __restrict__ d5)
{
    const int stride = gridDim.x * 256;
    for (int i = blockIdx.x * 256 + threadIdx.x; i < C6; i += stride) {
        const float* s; __hip_bfloat16* d; int off;
        if      (i < C1) { s = s0; d = d0; off = i; }
        else if (i < C2) { s = s1; d = d1; off = i - C1; }
        else if (i < C3) { s = s2; d = d2; off = i - C2; }
        else if (i < C4) { s = s3; d = d3; off = i - C3; }
        else if (i < C5) { s = s4; d = d4; off = i - C4; }
        else             { s = s5; d = d5; off = i - C5; }
        const float4* p = (const float4*)(s + (size_t)off * 8);
        float4 a = p[0], b = p[1];
        *(bfrag*)(d + (size_t)off * 8) = cvt8(a, b);
    }
}

// ====== ring-4 half-tile pipeline, 3-deep prefetch, counted vmcnt ======
// Half-tile = BK/2 = 32 cols. Phase p: {vmcnt(8); s_barrier; STAGE(p+3) into
// H[(p+3)&3]; ds_read H[p&3]; 32 MFMA}. One barrier/phase. Loads land 3 phases
// after issue (~900+ cy cover). Epilogue issues clamped duplicate stages
// (identical bytes into a dead buffer) to keep the per-wave ledger uniform.
// LDS half layout (verified 0-conflict in R5):
//   L(row,slot16) = (row>>1)*128 + (((slot + 4*(row&1)) ^ ((row>>1)&7)) << 4)
// linear dest (16*tid) + inverse-swizzled global source; read offset is the
// per-lane constant arb = (l15>>1)*128 + (((lhi+4*(l15&1)) ^ (l15>>1))<<4).

// fused gate+up: act = silu(X@W1^T) * (X@W3^T). BM=256, BN=128.
template<int N, bool GATHER>
__global__ __launch_bounds__(512, 2) void up_v6(
    const __hip_bfloat16* __restrict__ X,
    const __hip_bfloat16* __restrict__ W1,
    const __hip_bfloat16* __restrict__ W3,
    __hip_bfloat16* __restrict__ act,
    const int* __restrict__ list,
    const int* __restrict__ meta)
{
    constexpr int K = DIM;
    constexpr int NP = K / 32;   // 64 phases
    constexpr int nx = N / 128, ny = T_TOK / 256, nz = GATHER ? NEXP : 1;
    constexpr int nwg = nx * ny * nz, cpx = nwg / 8;
    const int bid = (int)blockIdx.x + nx * ((int)blockIdx.y + ny * (int)blockIdx.z);
    const int virt = (bid & 7) * cpx + (bid >> 3);
    const int xi = virt % nx;
    const int rest = virt / nx;
    const int yi = rest % ny;
    const int e = rest / ny;

    int count, base;
    if (GATHER) {
        count = meta[e]; base = meta[16 + e];
        if (yi * 256 >= count) return;
    } else { count = T_TOK; base = 0; }
    const int m0 = yi * 256, n0 = xi * 128;

    __shared__ alignas(16) short As[4][256 * 32];    // 64 KB
    __shared__ alignas(16) short B1s[4][128 * 32];   // 32 KB
    __shared__ alignas(16) short B3s[4][128 * 32];   // 32 KB

    const int tid = threadIdx.x, wid = tid >> 6, lane = tid & 63;

    // stage source mapping (inverse of the LDS layout)
    const int u    = (tid & 7) ^ ((tid >> 3) & 7);
    const int srow = 2 * (tid >> 3) + (u >> 2);    // 0..127
    const int sslot = u & 3;

    const __hip_bfloat16* pA[2];
#pragma unroll
    for (int q = 0; q < 2; ++q) {
        int r = m0 + srow + q * 128; if (r > count - 1) r = count - 1;
        int ga = GATHER ? list[base + r] : r;
        pA[q] = X + (size_t)ga * K + sslot * 8;
    }
    const __hip_bfloat16* pB1 = W1 + ((size_t)e * N + n0 + srow) * K + sslot * 8;
    const __hip_bfloat16* pB3 = W3 + ((size_t)e * N + n0 + srow) * K + sslot * 8;

#define STAGE_UP(H, BUF) do { const int k0_ = (H) * 32;                         \
    gload16(pA[0] + k0_, &As[BUF][tid * 8]);                                    \
    gload16(pA[1] + k0_, &As[BUF][4096 + tid * 8]);                             \
    gload16(pB1   + k0_, &B1s[BUF][tid * 8]);                                   \
    gload16(pB3   + k0_, &B3s[BUF][tid * 8]); } while (0)

    const int wm = wid >> 2, wn = wid & 3;
    const int l15 = lane & 15, lhi = lane >> 4;
    const int vswz = (((lhi + 4 * (l15 & 1)) ^ (l15 >> 1)) << 4);
    const int arb  = (l15 >> 1) * 128 + vswz;      // bytes within a half

    f32x4 accg[8][2], accu[8][2];
#pragma unroll
    for (int i = 0; i < 8; ++i)
#pragma unroll
        for (int j = 0; j < 2; ++j) { accg[i][j] = 0.f; accu[i][j] = 0.f; }

    // prologue: 3 half-stages in flight
    STAGE_UP(0, 0);
    STAGE_UP(1, 1);
    STAGE_UP(2, 2);

#pragma unroll 4
    for (int p = 0; p < NP; ++p) {
        const int cur = p & 3;
        asm volatile("s_waitcnt vmcnt(8)" ::: "memory");   // stage p landed
        __builtin_amdgcn_s_barrier();                      // all waves' stage p in LDS;
        __builtin_amdgcn_sched_barrier(0);                 // buf (p+3)&3 reads done @ p-1
        const int ps = (p + 3 < NP) ? (p + 3) : (NP - 1);  // clamped dup is benign
        STAGE_UP(ps, (p + 3) & 3);
        __builtin_amdgcn_sched_barrier(0);
        bfrag b1f[2], b3f[2];
#pragma unroll
        for (int j = 0; j < 2; ++j) {
            const int off = wn * 2048 + j * 1024 + arb;
            b1f[j] = *(const bfrag*)((const char*)B1s[cur] + off);
            b3f[j] = *(const bfrag*)((const char*)B3s[cur] + off);
        }
        __builtin_amdgcn_s_setprio(1);
#pragma unroll
        for (int i = 0; i < 8; ++i) {
            bfrag a = *(const bfrag*)((const char*)As[cur] + wm * 8192 + i * 1024 + arb);
#pragma unroll
            for (int j = 0; j < 2; ++j) {
                accg[i][j] = MFMA16(a, b1f[j], accg[i][j]);
                accu[i][j] = MFMA16(a, b3f[j], accu[i][j]);
            }
        }
        __builtin_amdgcn_s_setprio(0);
    }
#undef STAGE_UP
    asm volatile("s_waitcnt vmcnt(0)" ::: "memory");

#pragma unroll
    for (int i = 0; i < 8; ++i)
#pragma unroll
        for (int r = 0; r < 4; ++r) {
            int m = wm * 128 + i * 16 + lhi * 4 + r;
            if (m0 + m < count) {
#pragma unroll
                for (int j = 0; j < 2; ++j) {
                    float gg = accg[i][j][r];
                    float uu = accu[i][j][r];
                    float a = gg / (1.f + __expf(-gg)) * uu;   // silu(g)*u
                    int n = n0 + wn * 32 + j * 16 + l15;
                    act[(size_t)(base + m0 + m) * N + n] = __float2bfloat16(a);
                }
            }
        }
}

// down: y = A @ W2^T. BM=256, BN=256.
// TO_BF16: store unscaled bf16 rows to yscr (expert path; combine applies s_e).
// else:    store f32 rows straight to out (shared path).
template<int KD, bool TO_BF16>
__global__ __launch_bounds__(512, 2) void down_v6(
    const __hip_bfloat16* __restrict__ A,
    const __hip_bfloat16* __restrict__ W2,
    float* __restrict__ out,
    __hip_bfloat16* __restrict__ yscr,
    const int* __restrict__ meta)
{
    constexpr int N = DIM;
    constexpr int NP = KD / 32;
    constexpr int nx = N / 256, ny = T_TOK / 256, nz = TO_BF16 ? NEXP : 1;
    constexpr int nwg = nx * ny * nz, cpx = nwg / 8;
    const int bid = (int)blockIdx.x + nx * ((int)blockIdx.y + ny * (int)blockIdx.z);
    const int virt = (bid & 7) * cpx + (bid >> 3);
    const int xi = virt % nx;
    const int rest = virt / nx;
    const int yi = rest % ny;
    const int e = rest / ny;

    int count, base;
    if (TO_BF16) {
        count = meta[e]; base = meta[16 + e];
        if (yi * 256 >= count) return;
    } else { count = T_TOK; base = 0; }
    const int m0 = yi * 256, n0 = xi * 256;

    __shared__ alignas(16) short As[4][256 * 32];   // 64 KB
    __shared__ alignas(16) short Bs[4][256 * 32];   // 64 KB

    const int tid = threadIdx.x, wid = tid >> 6, lane = tid & 63;

    const int u    = (tid & 7) ^ ((tid >> 3) & 7);
    const int srow = 2 * (tid >> 3) + (u >> 2);
    const int sslot = u & 3;

    const __hip_bfloat16* pA[2];
    const __hip_bfloat16* pB[2];
#pragma unroll
    for (int q = 0; q < 2; ++q) {
        int r = m0 + srow + q * 128; if (r > count - 1) r = count - 1;
        pA[q] = A  + (size_t)(base + r) * KD + sslot * 8;
        pB[q] = W2 + ((size_t)e * N + n0 + srow + q * 128) * KD + sslot * 8;
    }

#define STAGE_DN(H, BUF) do { const int k0_ = (H) * 32;                         \
    gload16(pA[0] + k0_, &As[BUF][tid * 8]);                                    \
    gload16(pA[1] + k0_, &As[BUF][4096 + tid * 8]);                             \
    gload16(pB[0] + k0_, &Bs[BUF][tid * 8]);                                    \
    gload16(pB[1] + k0_, &Bs[BUF][4096 + tid * 8]); } while (0)

    const int wm = wid >> 2, wn = wid & 3;
    const int l15 = lane & 15, lhi = lane >> 4;
    const int vswz = (((lhi + 4 * (l15 & 1)) ^ (l15 >> 1)) << 4);
    const int arb  = (l15 >> 1) * 128 + vswz;

    f32x4 acc[8][4];
#pragma unroll
    for (int i = 0; i < 8; ++i)
#pragma unroll
        for (int j = 0; j < 4; ++j) acc[i][j] = 0.f;

    STAGE_DN(0, 0);
    STAGE_DN(1, 1);
    STAGE_DN(2, 2);

#pragma unroll 4
    for (int p = 0; p < NP; ++p) {
        const int cur = p & 3;
        asm volatile("s_waitcnt vmcnt(8)" ::: "memory");
        __builtin_amdgcn_s_barrier();
        __builtin_amdgcn_sched_barrier(0);
        const int ps = (p + 3 < NP) ? (p + 3) : (NP - 1);
        STAGE_DN(ps, (p + 3) & 3);
        __builtin_amdgcn_sched_barrier(0);
        bfrag bf[4];
#pragma unroll
        for (int j = 0; j < 4; ++j)
            bf[j] = *(const bfrag*)((const char*)Bs[cur] + wn * 4096 + j * 1024 + arb);
        __builtin_amdgcn_s_setprio(1);
#pragma unroll
        for (int i = 0; i < 8; ++i) {
            bfrag a = *(const bfrag*)((const char*)As[cur] + wm * 8192 + i * 1024 + arb);
#pragma unroll
            for (int j = 0; j < 4; ++j)
                acc[i][j] = MFMA16(a, bf[j], acc[i][j]);
        }
        __builtin_amdgcn_s_setprio(0);
    }
#undef STAGE_DN
    asm volatile("s_waitcnt vmcnt(0)" ::: "memory");

#pragma unroll
    for (int i = 0; i < 8; ++i)
#pragma unroll
        for (int r = 0; r < 4; ++r) {
            int m = wm * 128 + i * 16 + lhi * 4 + r;
            if (m0 + m < count) {
#pragma unroll
                for (int j = 0; j < 4; ++j) {
                    int n = n0 + wn * 64 + j * 16 + l15;
                    if (TO_BF16)
                        yscr[(size_t)(base + m0 + m) * DIM + n] = __float2bfloat16(acc[i][j][r]);
                    else
                        out[(size_t)(m0 + m) * DIM + n] = acc[i][j][r];
                }
            }
        }
}

// out[t] += s_e[e0]*y[slot0] + s_e[e1]*y[slot1]
__global__ __launch_bounds__(256) void combine_kernel(
    float* __restrict__ out, const __hip_bfloat16* __restrict__ yscr,
    const int* __restrict__ sel, const int2* __restrict__ slots,
    const float* __restrict__ s_e)
{
    const int t = blockIdx.x;
    const int d = threadIdx.x * 8;
    const int2 sl = slots[t];
    const float se0 = s_e[sel[2 * t]];
    const float se1 = s_e[sel[2 * t + 1]];
    bfrag y0 = *(const bfrag*)&yscr[(size_t)sl.x * DIM + d];
    bfrag y1 = *(const bfrag*)&yscr[(size_t)sl.y * DIM + d];
    float4* o = (float4*)(out + (size_t)t * DIM + d);
    float4 o0 = o[0], o1 = o[1];
    o0.x += se0 * bf2f(y0[0]) + se1 * bf2f(y1[0]);
    o0.y += se0 * bf2f(y0[1]) + se1 * bf2f(y1[1]);
    o0.z += se0 * bf2f(y0[2]) + se1 * bf2f(y1[2]);
    o0.w += se0 * bf2f(y0[3]) + se1 * bf2f(y1[3]);
    o1.x += se0 * bf2f(y0[4]) + se1 * bf2f(y1[4]);
    o1.y += se0 * bf2f(y0[5]) + se1 * bf2f(y1[5]);
    o1.z += se0 * bf2f(y0[6]) + se1 * bf2f(y1[6]);
    o1.w += se0 * bf2f(y0[7]) + se1 * bf2f(y1[7]);
    o[0] = o0; o[1] = o1;
}

extern "C" void kernel_launch(void* const* d_in, const int* in_sizes, int n_in,
                              void* d_out, int out_size, void* d_ws, size_t ws_size,
                              hipStream_t stream) {
    const float* x   = (const float*)d_in[0];
    const float* gw  = (const float*)d_in[1];
    const float* w1  = (const float*)d_in[2];
    const float* w3  = (const float*)d_in[3];
    const float* w2  = (const float*)d_in[4];
    const float* sw1 = (const float*)d_in[5];
    const float* sw3 = (const float*)d_in[6];
    const float* sw2 = (const float*)d_in[7];
    float* out = (float*)d_out;

    const size_t SZ_X   = (size_t)T_TOK * DIM * 2;            // 32 MB
    const size_t SZ_W   = (size_t)NEXP * HDIM * DIM * 2;      // 46.1 MB each
    const size_t SZ_SW  = (size_t)SHDIM * DIM * 2;            // 11.5 MB each
    const size_t SZ_ACT = (size_t)2 * T_TOK * HDIM * 2;       // 46.1 MB
    const size_t need = SZ_X + 3 * SZ_W + 3 * SZ_SW + SZ_ACT
                      + (size_t)4 * T_TOK * sizeof(int)
                      + (size_t)2 * T_TOK * sizeof(int) /*slots*/ + 512;
    if (need > ws_size) return;

    char* p = (char*)d_ws;
    __hip_bfloat16* xbf   = (__hip_bfloat16*)p; p += SZ_X;
    __hip_bfloat16* w1bf  = (__hip_bfloat16*)p; p += SZ_W;
    __hip_bfloat16* w3bf  = (__hip_bfloat16*)p; p += SZ_W;
    __hip_bfloat16* w2bf  = (__hip_bfloat16*)p; p += SZ_W;
    __hip_bfloat16* sw1bf = (__hip_bfloat16*)p; p += SZ_SW;
    __hip_bfloat16* sw3bf = (__hip_bfloat16*)p; p += SZ_SW;
    __hip_bfloat16* sw2bf = (__hip_bfloat16*)p; p += SZ_SW;
    __hip_bfloat16* act   = (__hip_bfloat16*)p; p += SZ_ACT;
    int*  list  = (int*)p;  p += (size_t)2 * T_TOK * sizeof(int);
    int*  sel   = (int*)p;  p += (size_t)2 * T_TOK * sizeof(int);
    int2* slots = (int2*)p; p += (size_t)2 * T_TOK * sizeof(int);
    int*  meta  = (int*)p;
    float* s_e  = (float*)(meta + 32);
    // y scratch (16384 x 2048 bf16 = 64 MB) aliases xbf+w1bf (dead after expert-up)
    __hip_bfloat16* yscr = (__hip_bfloat16*)d_ws;

    hipMemsetAsync(meta, 0, 256, stream);
    gate_kernel<<<T_TOK / 32, 256, 0, stream>>>(x, gw, xbf, sel, meta, s_e);
    scan_kernel<<<1, 64, 0, stream>>>(meta);
    fill_kernel<<<T_TOK / 256, 256, 0, stream>>>(sel, meta, list, slots);

    cvt6_kernel<<<2048, 256, 0, stream>>>(w1, w3, w2, sw1, sw3, sw2,
                                          w1bf, w3bf, w2bf, sw1bf, sw3bf, sw2bf);

    // shared expert first (plain f32 stores init out)
    up_v6<SHDIM, false><<<dim3(SHDIM / 128, T_TOK / 256, 1), 512, 0, stream>>>(
        xbf, sw1bf, sw3bf, act, nullptr, meta);
    down_v6<SHDIM, false><<<dim3(DIM / 256, T_TOK / 256, 1), 512, 0, stream>>>(
        act, sw2bf, out, nullptr, meta);
    // sparse experts: act -> y (bf16, unscaled) -> combine with s_e scales
    up_v6<HDIM, true><<<dim3(HDIM / 128, T_TOK / 256, NEXP), 512, 0, stream>>>(
        xbf, w1bf, w3bf, act, list, meta);
    down_v6<HDIM, true><<<dim3(DIM / 256, T_TOK / 256, NEXP), 512, 0, stream>>>(
        act, w2bf, out, yscr, meta);
    combine_kernel<<<T_TOK, 256, 0, stream>>>(out, yscr, sel, slots, s_e);
}

// Round 7
// 1105.251 us; speedup vs baseline: 1.1467x; 1.0119x over previous
//
#include <hip/hip_runtime.h>
#include <hip/hip_bf16.h>
#include <stdint.h>

#define T_TOK 8192
#define DIM   2048
#define NEXP  8
#define HDIM  1408
#define SHDIM 2816

typedef __attribute__((ext_vector_type(8))) short bfrag;   // 8 x bf16 (4 VGPR)
typedef __attribute__((ext_vector_type(4))) float f32x4;
typedef __attribute__((ext_vector_type(4))) short s16x4;

__device__ __forceinline__ short f2bf(float f) {
    union { float f; uint32_t u; } v; v.f = f;
    return (short)((v.u + 0x8000u) >> 16);   // round-half-up bf16
}
__device__ __forceinline__ float bf2f(short s) {
    union { uint32_t u; float f; } v; v.u = ((uint32_t)(uint16_t)s) << 16;
    return v.f;
}

__device__ __forceinline__ bfrag cvt8(float4 a, float4 b) {
    bfrag r;
    r[0] = f2bf(a.x); r[1] = f2bf(a.y); r[2] = f2bf(a.z); r[3] = f2bf(a.w);
    r[4] = f2bf(b.x); r[5] = f2bf(b.y); r[6] = f2bf(b.z); r[7] = f2bf(b.w);
    return r;
}

__device__ __forceinline__ void gload16(const void* g, void* l) {
    __builtin_amdgcn_global_load_lds(
        (__attribute__((address_space(1))) void*)(g),
        (__attribute__((address_space(3))) void*)(l), 16, 0, 0);
}

#define MFMA16(a, b, c) __builtin_amdgcn_mfma_f32_16x16x32_bf16((a), (b), (c), 0, 0, 0)
#define LGKM0_FENCE() do { asm volatile("s_waitcnt lgkmcnt(0)" ::: "memory"); \
                           __builtin_amdgcn_sched_barrier(0); } while (0)

// meta: ints [0..7] counts, [8..15] cursor, [16..24] offsets; floats at +32: s_e[8]

__global__ __launch_bounds__(256) void gate_kernel(
    const float* __restrict__ x, const float* __restrict__ gw,
    __hip_bfloat16* __restrict__ xbf,
    int* __restrict__ sel, int* __restrict__ meta, float* __restrict__ s_e)
{
    __shared__ float g[NEXP * DIM];            // 64 KB
    for (int i = threadIdx.x; i < NEXP * DIM; i += 256) g[i] = gw[i];
    __syncthreads();
    const int wid = threadIdx.x >> 6, lane = threadIdx.x & 63;
    for (int it = 0; it < 8; ++it) {
        const int t = blockIdx.x * 32 + wid * 8 + it;
        float acc[NEXP];
#pragma unroll
        for (int e = 0; e < NEXP; ++e) acc[e] = 0.f;
        const float4* xr = (const float4*)(x + (size_t)t * DIM);
        for (int j = 0; j < DIM / 4; j += 64) {
            float4 xv = xr[j + lane];
            s16x4 xv16 = { f2bf(xv.x), f2bf(xv.y), f2bf(xv.z), f2bf(xv.w) };
            *(s16x4*)&xbf[(size_t)t * DIM + (j + lane) * 4] = xv16;
#pragma unroll
            for (int e = 0; e < NEXP; ++e) {
                float4 gv = *(const float4*)&g[e * DIM + (j + lane) * 4];
                acc[e] += xv.x * gv.x + xv.y * gv.y + xv.z * gv.z + xv.w * gv.w;
            }
        }
#pragma unroll
        for (int e = 0; e < NEXP; ++e)
            for (int o = 32; o; o >>= 1) acc[e] += __shfl_xor(acc[e], o);
        if (lane == 0) {
            int e0 = 0; float v0 = acc[0];
#pragma unroll
            for (int e = 1; e < NEXP; ++e) if (acc[e] > v0) { v0 = acc[e]; e0 = e; }
            int e1 = -1; float v1 = -3.4e38f;
#pragma unroll
            for (int e = 0; e < NEXP; ++e) if (e != e0 && acc[e] > v1) { v1 = acc[e]; e1 = e; }
            float p0 = 1.f / (1.f + __expf(v1 - v0));
            float p1 = 1.f - p0;
            sel[2 * t] = e0; sel[2 * t + 1] = e1;
            atomicAdd(&s_e[e0], p0); atomicAdd(&s_e[e1], p1);
            atomicAdd(&meta[e0], 1); atomicAdd(&meta[e1], 1);
        }
    }
}

__global__ void scan_kernel(int* meta) {
    if (threadIdx.x == 0) {
        int acc = 0;
        for (int e = 0; e < NEXP; ++e) {
            meta[16 + e] = acc;
            meta[8 + e]  = acc;
            acc += meta[e];
        }
        meta[24] = acc;
    }
}

__global__ __launch_bounds__(256) void fill_kernel(
    const int* __restrict__ sel, int* __restrict__ meta,
    int* __restrict__ list, int2* __restrict__ slots)
{
    const int t = blockIdx.x * 256 + threadIdx.x;
    int e0 = sel[2 * t], e1 = sel[2 * t + 1];
    int p0 = atomicAdd(&meta[8 + e0], 1); list[p0] = t;
    int p1 = atomicAdd(&meta[8 + e1], 1); list[p1] = t;
    slots[t] = make_int2(p0, p1);
}

// one fused fp32->bf16 conversion for the 6 weight tensors
#define C1 2883584
#define C2 5767168
#define C3 8650752
#define C4 9371648
#define C5 10092544
#define C6 10813440
__global__ __launch_bounds__(256) void cvt6_kernel(
    const float* __restrict__ s0, const float* __restrict__ s1, const float* __restrict__ s2,
    const float* __restrict__ s3, const float* __restrict__ s4, const float* __restrict__ s5,
    __hip_bfloat16* __restrict__ d0, __hip_bfloat16* __restrict__ d1, __hip_bfloat16* __restrict__ d2,
    __hip_bfloat16* __restrict__ d3, __hip_bfloat16* __restrict__ d4, __hip_bfloat16* __restrict__ d5)
{
    const int stride = gridDim.x * 256;
    for (int i = blockIdx.x * 256 + threadIdx.x; i < C6; i += stride) {
        const float* s; __hip_bfloat16* d; int off;
        if      (i < C1) { s = s0; d = d0; off = i; }
        else if (i < C2) { s = s1; d = d1; off = i - C1; }
        else if (i < C3) { s = s2; d = d2; off = i - C2; }
        else if (i < C4) { s = s3; d = d3; off = i - C3; }
        else if (i < C5) { s = s4; d = d4; off = i - C4; }
        else             { s = s5; d = d5; off = i - C5; }
        const float4* p = (const float4*)(s + (size_t)off * 8);
        float4 a = p[0], b = p[1];
        *(bfrag*)(d + (size_t)off * 8) = cvt8(a, b);
    }
}

// ====== ring-4 half-tile pipeline + m201 sub-phase discipline ======
// Memory system (R6, verified): ring of 4 half-buffers (32 k-cols), 3-deep
// prefetch, vmcnt(8) at phase top, stage-after-top-barrier.
// Compute (m201): 2 sub-phases of 16 MFMA per half; each sub-phase =
// {stage 2 gloads; ds_read cluster -> regs; s_barrier; lgkmcnt(0)+SBAR0;
//  setprio(1); 16 MFMA (pure register); setprio(0); s_barrier(=next top)}.
// LDS half layout (verified 0-conflict):
//   L(row,slot16) = (row>>1)*128 + (((slot + 4*(row&1)) ^ ((row>>1)&7)) << 4)

// fused gate+up: act = silu(X@W1^T) * (X@W3^T). BM=256, BN=128.
template<int N, bool GATHER>
__global__ __launch_bounds__(512, 2) void up_v7(
    const __hip_bfloat16* __restrict__ X,
    const __hip_bfloat16* __restrict__ W1,
    const __hip_bfloat16* __restrict__ W3,
    __hip_bfloat16* __restrict__ act,
    const int* __restrict__ list,
    const int* __restrict__ meta)
{
    constexpr int K = DIM;
    constexpr int NP = K / 32;   // 64 phases
    constexpr int nx = N / 128, ny = T_TOK / 256, nz = GATHER ? NEXP : 1;
    constexpr int nwg = nx * ny * nz, cpx = nwg / 8;
    const int bid = (int)blockIdx.x + nx * ((int)blockIdx.y + ny * (int)blockIdx.z);
    const int virt = (bid & 7) * cpx + (bid >> 3);
    const int xi = virt % nx;
    const int rest = virt / nx;
    const int yi = rest % ny;
    const int e = rest / ny;

    int count, base;
    if (GATHER) {
        count = meta[e]; base = meta[16 + e];
        if (yi * 256 >= count) return;
    } else { count = T_TOK; base = 0; }
    const int m0 = yi * 256, n0 = xi * 128;

    __shared__ alignas(16) short As[4][256 * 32];    // 64 KB
    __shared__ alignas(16) short B1s[4][128 * 32];   // 32 KB
    __shared__ alignas(16) short B3s[4][128 * 32];   // 32 KB

    const int tid = threadIdx.x, wid = tid >> 6, lane = tid & 63;

    // stage source mapping (inverse of the LDS layout)
    const int u    = (tid & 7) ^ ((tid >> 3) & 7);
    const int srow = 2 * (tid >> 3) + (u >> 2);    // 0..127
    const int sslot = u & 3;

    const __hip_bfloat16* pA[2];
#pragma unroll
    for (int q = 0; q < 2; ++q) {
        int r = m0 + srow + q * 128; if (r > count - 1) r = count - 1;
        int ga = GATHER ? list[base + r] : r;
        pA[q] = X + (size_t)ga * K + sslot * 8;
    }
    const __hip_bfloat16* pB1 = W1 + ((size_t)e * N + n0 + srow) * K + sslot * 8;
    const __hip_bfloat16* pB3 = W3 + ((size_t)e * N + n0 + srow) * K + sslot * 8;

    const int wm = wid >> 2, wn = wid & 3;
    const int l15 = lane & 15, lhi = lane >> 4;
    const int vswz = (((lhi + 4 * (l15 & 1)) ^ (l15 >> 1)) << 4);
    const int arb  = (l15 >> 1) * 128 + vswz;      // bytes within a half

    f32x4 accg[8][2], accu[8][2];
#pragma unroll
    for (int i = 0; i < 8; ++i)
#pragma unroll
        for (int j = 0; j < 2; ++j) { accg[i][j] = 0.f; accu[i][j] = 0.f; }

    // prologue: 3 half-stages in flight (4 gloads each)
#define STAGE_ALL(H, BUF) do { const int k0_ = (H) * 32;                        \
    gload16(pA[0] + k0_, &As[BUF][tid * 8]);                                    \
    gload16(pA[1] + k0_, &As[BUF][4096 + tid * 8]);                             \
    gload16(pB1   + k0_, &B1s[BUF][tid * 8]);                                   \
    gload16(pB3   + k0_, &B3s[BUF][tid * 8]); } while (0)
    STAGE_ALL(0, 0);
    STAGE_ALL(1, 1);
    STAGE_ALL(2, 2);
#undef STAGE_ALL

#pragma unroll 4
    for (int p = 0; p < NP; ++p) {
        const int cur = p & 3;
        const int ps = (p + 3 < NP) ? (p + 3) : (NP - 1);  // clamped dup benign
        const int pb = (p + 3) & 3;
        const int k0s = ps * 32;

        // ---- sub-phase 0: i 0..3, reads B(4)+A(4) ----
        asm volatile("s_waitcnt vmcnt(8)" ::: "memory");   // own H[p] landed
        __builtin_amdgcn_s_barrier();                      // collective: H[p] ready, H[p-1] reads done
        __builtin_amdgcn_sched_barrier(0);
        gload16(pA[0] + k0s, &As[pb][tid * 8]);            // stage chunk 0
        gload16(pA[1] + k0s, &As[pb][4096 + tid * 8]);
        __builtin_amdgcn_sched_barrier(0);
        bfrag b1f[2], b3f[2], af[4];
#pragma unroll
        for (int j = 0; j < 2; ++j) {
            const int off = wn * 2048 + j * 1024 + arb;
            b1f[j] = *(const bfrag*)((const char*)B1s[cur] + off);
            b3f[j] = *(const bfrag*)((const char*)B3s[cur] + off);
        }
#pragma unroll
        for (int i = 0; i < 4; ++i)
            af[i] = *(const bfrag*)((const char*)As[cur] + wm * 8192 + i * 1024 + arb);
        __builtin_amdgcn_s_barrier();                      // mid barrier (absorbs ds latency)
        LGKM0_FENCE();
        __builtin_amdgcn_s_setprio(1);
#pragma unroll
        for (int i = 0; i < 4; ++i)
#pragma unroll
            for (int j = 0; j < 2; ++j) {
                accg[i][j] = MFMA16(af[i], b1f[j], accg[i][j]);
                accu[i][j] = MFMA16(af[i], b3f[j], accu[i][j]);
            }
        __builtin_amdgcn_s_setprio(0);
        __builtin_amdgcn_s_barrier();

        // ---- sub-phase 1: i 4..7, reads A(4) ----
        __builtin_amdgcn_sched_barrier(0);
        gload16(pB1 + k0s, &B1s[pb][tid * 8]);             // stage chunk 1
        gload16(pB3 + k0s, &B3s[pb][tid * 8]);
        __builtin_amdgcn_sched_barrier(0);
        bfrag ag[4];
#pragma unroll
        for (int i = 0; i < 4; ++i)
            ag[i] = *(const bfrag*)((const char*)As[cur] + wm * 8192 + (4 + i) * 1024 + arb);
        __builtin_amdgcn_s_barrier();
        LGKM0_FENCE();
        __builtin_amdgcn_s_setprio(1);
#pragma unroll
        for (int i = 0; i < 4; ++i)
#pragma unroll
            for (int j = 0; j < 2; ++j) {
                accg[4 + i][j] = MFMA16(ag[i], b1f[j], accg[4 + i][j]);
                accu[4 + i][j] = MFMA16(ag[i], b3f[j], accu[4 + i][j]);
            }
        __builtin_amdgcn_s_setprio(0);
        __builtin_amdgcn_s_barrier();                      // = next phase top
    }
    asm volatile("s_waitcnt vmcnt(0)" ::: "memory");

#pragma unroll
    for (int i = 0; i < 8; ++i)
#pragma unroll
        for (int r = 0; r < 4; ++r) {
            int m = wm * 128 + i * 16 + lhi * 4 + r;
            if (m0 + m < count) {
#pragma unroll
                for (int j = 0; j < 2; ++j) {
                    float gg = accg[i][j][r];
                    float uu = accu[i][j][r];
                    float a = gg / (1.f + __expf(-gg)) * uu;   // silu(g)*u
                    int n = n0 + wn * 32 + j * 16 + l15;
                    act[(size_t)(base + m0 + m) * N + n] = __float2bfloat16(a);
                }
            }
        }
}

// down: y = A @ W2^T. BM=256, BN=256.
// TO_BF16: store unscaled bf16 rows to yscr (expert path; combine applies s_e).
// else:    store f32 rows straight to out (shared path).
template<int KD, bool TO_BF16>
__global__ __launch_bounds__(512, 2) void down_v7(
    const __hip_bfloat16* __restrict__ A,
    const __hip_bfloat16* __restrict__ W2,
    float* __restrict__ out,
    __hip_bfloat16* __restrict__ yscr,
    const int* __restrict__ meta)
{
    constexpr int N = DIM;
    constexpr int NP = KD / 32;
    constexpr int nx = N / 256, ny = T_TOK / 256, nz = TO_BF16 ? NEXP : 1;
    constexpr int nwg = nx * ny * nz, cpx = nwg / 8;
    const int bid = (int)blockIdx.x + nx * ((int)blockIdx.y + ny * (int)blockIdx.z);
    const int virt = (bid & 7) * cpx + (bid >> 3);
    const int xi = virt % nx;
    const int rest = virt / nx;
    const int yi = rest % ny;
    const int e = rest / ny;

    int count, base;
    if (TO_BF16) {
        count = meta[e]; base = meta[16 + e];
        if (yi * 256 >= count) return;
    } else { count = T_TOK; base = 0; }
    const int m0 = yi * 256, n0 = xi * 256;

    __shared__ alignas(16) short As[4][256 * 32];   // 64 KB
    __shared__ alignas(16) short Bs[4][256 * 32];   // 64 KB

    const int tid = threadIdx.x, wid = tid >> 6, lane = tid & 63;

    const int u    = (tid & 7) ^ ((tid >> 3) & 7);
    const int srow = 2 * (tid >> 3) + (u >> 2);
    const int sslot = u & 3;

    const __hip_bfloat16* pA[2];
    const __hip_bfloat16* pB[2];
#pragma unroll
    for (int q = 0; q < 2; ++q) {
        int r = m0 + srow + q * 128; if (r > count - 1) r = count - 1;
        pA[q] = A  + (size_t)(base + r) * KD + sslot * 8;
        pB[q] = W2 + ((size_t)e * N + n0 + srow + q * 128) * KD + sslot * 8;
    }

    const int wm = wid >> 2, wn = wid & 3;
    const int l15 = lane & 15, lhi = lane >> 4;
    const int vswz = (((lhi + 4 * (l15 & 1)) ^ (l15 >> 1)) << 4);
    const int arb  = (l15 >> 1) * 128 + vswz;

    f32x4 acc[8][4];
#pragma unroll
    for (int i = 0; i < 8; ++i)
#pragma unroll
        for (int j = 0; j < 4; ++j) acc[i][j] = 0.f;

#define STAGE_ALL(H, BUF) do { const int k0_ = (H) * 32;                        \
    gload16(pA[0] + k0_, &As[BUF][tid * 8]);                                    \
    gload16(pA[1] + k0_, &As[BUF][4096 + tid * 8]);                             \
    gload16(pB[0] + k0_, &Bs[BUF][tid * 8]);                                    \
    gload16(pB[1] + k0_, &Bs[BUF][4096 + tid * 8]); } while (0)
    STAGE_ALL(0, 0);
    STAGE_ALL(1, 1);
    STAGE_ALL(2, 2);
#undef STAGE_ALL

#pragma unroll 4
    for (int p = 0; p < NP; ++p) {
        const int cur = p & 3;
        const int ps = (p + 3 < NP) ? (p + 3) : (NP - 1);
        const int pb = (p + 3) & 3;
        const int k0s = ps * 32;

        // ---- sub-phase 0: i 0..3, reads B(4)+A(4) ----
        asm volatile("s_waitcnt vmcnt(8)" ::: "memory");
        __builtin_amdgcn_s_barrier();
        __builtin_amdgcn_sched_barrier(0);
        gload16(pA[0] + k0s, &As[pb][tid * 8]);
        gload16(pA[1] + k0s, &As[pb][4096 + tid * 8]);
        __builtin_amdgcn_sched_barrier(0);
        bfrag bf[4], af[4];
#pragma unroll
        for (int j = 0; j < 4; ++j)
            bf[j] = *(const bfrag*)((const char*)Bs[cur] + wn * 4096 + j * 1024 + arb);
#pragma unroll
        for (int i = 0; i < 4; ++i)
            af[i] = *(const bfrag*)((const char*)As[cur] + wm * 8192 + i * 1024 + arb);
        __builtin_amdgcn_s_barrier();
        LGKM0_FENCE();
        __builtin_amdgcn_s_setprio(1);
#pragma unroll
        for (int i = 0; i < 4; ++i)
#pragma unroll
            for (int j = 0; j < 4; ++j)
                acc[i][j] = MFMA16(af[i], bf[j], acc[i][j]);
        __builtin_amdgcn_s_setprio(0);
        __builtin_amdgcn_s_barrier();

        // ---- sub-phase 1: i 4..7, reads A(4) ----
        __builtin_amdgcn_sched_barrier(0);
        gload16(pB[0] + k0s, &Bs[pb][tid * 8]);
        gload16(pB[1] + k0s, &Bs[pb][4096 + tid * 8]);
        __builtin_amdgcn_sched_barrier(0);
        bfrag ag[4];
#pragma unroll
        for (int i = 0; i < 4; ++i)
            ag[i] = *(const bfrag*)((const char*)As[cur] + wm * 8192 + (4 + i) * 1024 + arb);
        __builtin_amdgcn_s_barrier();
        LGKM0_FENCE();
        __builtin_amdgcn_s_setprio(1);
#pragma unroll
        for (int i = 0; i < 4; ++i)
#pragma unroll
            for (int j = 0; j < 4; ++j)
                acc[4 + i][j] = MFMA16(ag[i], bf[j], acc[4 + i][j]);
        __builtin_amdgcn_s_setprio(0);
        __builtin_amdgcn_s_barrier();
    }
    asm volatile("s_waitcnt vmcnt(0)" ::: "memory");

#pragma unroll
    for (int i = 0; i < 8; ++i)
#pragma unroll
        for (int r = 0; r < 4; ++r) {
            int m = wm * 128 + i * 16 + lhi * 4 + r;
            if (m0 + m < count) {
#pragma unroll
                for (int j = 0; j < 4; ++j) {
                    int n = n0 + wn * 64 + j * 16 + l15;
                    if (TO_BF16)
                        yscr[(size_t)(base + m0 + m) * DIM + n] = __float2bfloat16(acc[i][j][r]);
                    else
                        out[(size_t)(m0 + m) * DIM + n] = acc[i][j][r];
                }
            }
        }
}

// out[t] += s_e[e0]*y[slot0] + s_e[e1]*y[slot1]
__global__ __launch_bounds__(256) void combine_kernel(
    float* __restrict__ out, const __hip_bfloat16* __restrict__ yscr,
    const int* __restrict__ sel, const int2* __restrict__ slots,
    const float* __restrict__ s_e)
{
    const int t = blockIdx.x;
    const int d = threadIdx.x * 8;
    const int2 sl = slots[t];
    const float se0 = s_e[sel[2 * t]];
    const float se1 = s_e[sel[2 * t + 1]];
    bfrag y0 = *(const bfrag*)&yscr[(size_t)sl.x * DIM + d];
    bfrag y1 = *(const bfrag*)&yscr[(size_t)sl.y * DIM + d];
    float4* o = (float4*)(out + (size_t)t * DIM + d);
    float4 o0 = o[0], o1 = o[1];
    o0.x += se0 * bf2f(y0[0]) + se1 * bf2f(y1[0]);
    o0.y += se0 * bf2f(y0[1]) + se1 * bf2f(y1[1]);
    o0.z += se0 * bf2f(y0[2]) + se1 * bf2f(y1[2]);
    o0.w += se0 * bf2f(y0[3]) + se1 * bf2f(y1[3]);
    o1.x += se0 * bf2f(y0[4]) + se1 * bf2f(y1[4]);
    o1.y += se0 * bf2f(y0[5]) + se1 * bf2f(y1[5]);
    o1.z += se0 * bf2f(y0[6]) + se1 * bf2f(y1[6]);
    o1.w += se0 * bf2f(y0[7]) + se1 * bf2f(y1[7]);
    o[0] = o0; o[1] = o1;
}

extern "C" void kernel_launch(void* const* d_in, const int* in_sizes, int n_in,
                              void* d_out, int out_size, void* d_ws, size_t ws_size,
                              hipStream_t stream) {
    const float* x   = (const float*)d_in[0];
    const float* gw  = (const float*)d_in[1];
    const float* w1  = (const float*)d_in[2];
    const float* w3  = (const float*)d_in[3];
    const float* w2  = (const float*)d_in[4];
    const float* sw1 = (const float*)d_in[5];
    const float* sw3 = (const float*)d_in[6];
    const float* sw2 = (const float*)d_in[7];
    float* out = (float*)d_out;

    const size_t SZ_X   = (size_t)T_TOK * DIM * 2;            // 32 MB
    const size_t SZ_W   = (size_t)NEXP * HDIM * DIM * 2;      // 46.1 MB each
    const size_t SZ_SW  = (size_t)SHDIM * DIM * 2;            // 11.5 MB each
    const size_t SZ_ACT = (size_t)2 * T_TOK * HDIM * 2;       // 46.1 MB
    const size_t need = SZ_X + 3 * SZ_W + 3 * SZ_SW + SZ_ACT
                      + (size_t)4 * T_TOK * sizeof(int)
                      + (size_t)2 * T_TOK * sizeof(int) /*slots*/ + 512;
    if (need > ws_size) return;

    char* p = (char*)d_ws;
    __hip_bfloat16* xbf   = (__hip_bfloat16*)p; p += SZ_X;
    __hip_bfloat16* w1bf  = (__hip_bfloat16*)p; p += SZ_W;
    __hip_bfloat16* w3bf  = (__hip_bfloat16*)p; p += SZ_W;
    __hip_bfloat16* w2bf  = (__hip_bfloat16*)p; p += SZ_W;
    __hip_bfloat16* sw1bf = (__hip_bfloat16*)p; p += SZ_SW;
    __hip_bfloat16* sw3bf = (__hip_bfloat16*)p; p += SZ_SW;
    __hip_bfloat16* sw2bf = (__hip_bfloat16*)p; p += SZ_SW;
    __hip_bfloat16* act   = (__hip_bfloat16*)p; p += SZ_ACT;
    int*  list  = (int*)p;  p += (size_t)2 * T_TOK * sizeof(int);
    int*  sel   = (int*)p;  p += (size_t)2 * T_TOK * sizeof(int);
    int2* slots = (int2*)p; p += (size_t)2 * T_TOK * sizeof(int);
    int*  meta  = (int*)p;
    float* s_e  = (float*)(meta + 32);
    // y scratch (16384 x 2048 bf16 = 64 MB) aliases xbf+w1bf (dead after expert-up)
    __hip_bfloat16* yscr = (__hip_bfloat16*)d_ws;

    hipMemsetAsync(meta, 0, 256, stream);
    gate_kernel<<<T_TOK / 32, 256, 0, stream>>>(x, gw, xbf, sel, meta, s_e);
    scan_kernel<<<1, 64, 0, stream>>>(meta);
    fill_kernel<<<T_TOK / 256, 256, 0, stream>>>(sel, meta, list, slots);

    cvt6_kernel<<<2048, 256, 0, stream>>>(w1, w3, w2, sw1, sw3, sw2,
                                          w1bf, w3bf, w2bf, sw1bf, sw3bf, sw2bf);

    // shared expert first (plain f32 stores init out)
    up_v7<SHDIM, false><<<dim3(SHDIM / 128, T_TOK / 256, 1), 512, 0, stream>>>(
        xbf, sw1bf, sw3bf, act, nullptr, meta);
    down_v7<SHDIM, false><<<dim3(DIM / 256, T_TOK / 256, 1), 512, 0, stream>>>(
        act, sw2bf, out, nullptr, meta);
    // sparse experts: act -> y (bf16, unscaled) -> combine with s_e scales
    up_v7<HDIM, true><<<dim3(HDIM / 128, T_TOK / 256, NEXP), 512, 0, stream>>>(
        xbf, w1bf, w3bf, act, list, meta);
    down_v7<HDIM, true><<<dim3(DIM / 256, T_TOK / 256, NEXP), 512, 0, stream>>>(
        act, w2bf, out, yscr, meta);
    combine_kernel<<<T_TOK, 256, 0, stream>>>(out, yscr, sel, slots, s_e);
}